// Round 5
// baseline (1196.935 us; speedup 1.0000x reference)
//
#include <hip/hip_runtime.h>

typedef __attribute__((ext_vector_type(4))) float f32x4;
typedef __attribute__((ext_vector_type(8))) short short8x;

#define DIM   4096
#define NB    8
#define NN    2048
#define NROWS (NB*NN)
#define NQ    7
#define NHQ   56
#define SCALE 0.04419417382415922f  /* 1/sqrt(512) */
#define NBLKS 512
#define NLEAF 16
#define BPL   (NBLKS/NLEAF)

// ---- workspace layout (float offsets), ~24.1 MB used
#define OFF_MU     0L          /* 16384 */
#define OFF_RSTD   16384L      /* 16384 */
#define OFF_Q7     32768L      /* 28672 */
#define OFF_A      61440L      /* 64 */
#define OFF_D0     61504L      /* 64 */
#define OFF_S1     61568L      /* 64 */
#define OFF_SUMEXP 61632L      /* 448 */
#define OFF_CTXM   62528L      /* 32768 */
#define OFF_GFIN   95296L      /* 32768 */
#define OFF_YM     128064L     /* 262144 */
#define OFF_UGBF   390208L     /* 64*4096 ushorts = 131072 floats */
#define OFF_STATP  521280L     /* 4*16384 float2 = 131072 */
#define OFF_SCT    652352L     /* 56*16384 = 917504 used */
#define OFF_BAR    1600000L    /* 32 uints, in sct slack; 128B aligned */
#define OFF_BIG    1700928L    /* time-shared: upart 16*56*4096=3670016 ;
                                  raw 4*16384*64=4194304 ;
                                  am 131072 @+0, part 16*64*4096=4194304 @+131072 */
#define OFF_AM     (OFF_BIG)
#define OFF_PART   (OFF_BIG + 131072L)

__device__ __forceinline__ unsigned short f2bf(float f) {   // RNE
  union { float f; unsigned int u; } v; v.f = f;
  return (unsigned short)((v.u + 0x7FFFu + ((v.u >> 16) & 1u)) >> 16);
}
__device__ __forceinline__ unsigned short f2bfr(float f) {  // cheap round
  union { float f; unsigned int u; } v; v.f = f;
  return (unsigned short)((v.u + 0x8000u) >> 16);
}
__device__ __forceinline__ float waveSum(float v) {
  #pragma unroll
  for (int m = 1; m < 64; m <<= 1) v += __shfl_xor(v, m);
  return v;
}

// monotonic two-level grid barrier: bar[0]=gen, bar[1..16]=leaves, bar[17]=root
__device__ __forceinline__ void gbar(unsigned* bar, int k) {
  __syncthreads();
  if (threadIdx.x == 0) {
    __threadfence();
    unsigned* leaf = bar + 1 + (blockIdx.x & (NLEAF - 1));
    unsigned a = __hip_atomic_fetch_add(leaf, 1u, __ATOMIC_ACQ_REL, __HIP_MEMORY_SCOPE_AGENT);
    if (a == (unsigned)((k + 1) * BPL - 1)) {
      unsigned r = __hip_atomic_fetch_add(bar + 17, 1u, __ATOMIC_ACQ_REL, __HIP_MEMORY_SCOPE_AGENT);
      if (r == (unsigned)((k + 1) * NLEAF - 1))
        __hip_atomic_fetch_add(bar, 1u, __ATOMIC_ACQ_REL, __HIP_MEMORY_SCOPE_AGENT);
    }
    while (__hip_atomic_load(bar, __ATOMIC_ACQUIRE, __HIP_MEMORY_SCOPE_AGENT) < (unsigned)(k + 1))
      __builtin_amdgcn_s_sleep(8);
    __threadfence();
  }
  __syncthreads();
}

__global__ __launch_bounds__(256, 4) void k_mega(
    const float* __restrict__ x, const float* __restrict__ slots,
    const float* __restrict__ lng, const float* __restrict__ lnb,
    const float* __restrict__ ipw, const float* __restrict__ ipb,
    const float* __restrict__ opw, const float* __restrict__ opb,
    const float* __restrict__ alpha, float* __restrict__ out, float* __restrict__ ws) {
  __shared__ float smem[1024];
  const int bid = blockIdx.x, tid = threadIdx.x;
  const int w = tid >> 6, l = tid & 63;

  float* mu     = ws + OFF_MU;
  float* rstd   = ws + OFF_RSTD;
  float* q7     = ws + OFF_Q7;
  float* Aarr   = ws + OFF_A;
  float* D0arr  = ws + OFF_D0;
  float* s1     = ws + OFF_S1;
  float* sumexp = ws + OFF_SUMEXP;
  float* ctxm   = ws + OFF_CTXM;
  float* gfin   = ws + OFF_GFIN;
  float* ym     = ws + OFF_YM;
  unsigned short* ugbf = (unsigned short*)(ws + OFF_UGBF);
  float2* statp = (float2*)(ws + OFF_STATP);
  float* sct    = ws + OFF_SCT;
  unsigned* bar = (unsigned*)(ws + OFF_BAR);
  float* upart  = ws + OFF_BIG;
  float* raw    = ws + OFF_BIG;
  float* am     = ws + OFF_AM;
  float* part   = ws + OFF_PART;
  float* out_attn = out + (long)NROWS * DIM;

  // ===== P1: qproj (1024 virtual) + zero sumexp/s1 + zero ugbf pad rows =====
  if (bid == 0) {
    if (tid < 448) sumexp[tid] = 0.f;
    else if (tid < 512) s1[tid - 448] = 0.f;
  } else if (bid <= 8) {  // pad row 56+bid-1
    unsigned* u32 = (unsigned*)ugbf;
    const long r = 56 + bid - 1;
    #pragma unroll
    for (int j = 0; j < 8; j++) u32[r*2048 + (long)tid*8 + j] = 0u;
  }
  for (int vb = bid; vb < 1024; vb += NBLKS) {
    const int d = vb * 4 + w;
    const float4* wr4 = (const float4*)(ipw + (long)d * DIM);
    float acc[7] = {0,0,0,0,0,0,0};
    for (int e4 = l; e4 < 1024; e4 += 64) {
      float4 wv = wr4[e4];
      #pragma unroll
      for (int s = 0; s < 7; s++) {
        float4 sv = ((const float4*)(slots + (long)s*DIM))[e4];
        sv.x = fminf(fmaxf(sv.x, -10.f), 10.f); sv.y = fminf(fmaxf(sv.y, -10.f), 10.f);
        sv.z = fminf(fmaxf(sv.z, -10.f), 10.f); sv.w = fminf(fmaxf(sv.w, -10.f), 10.f);
        acc[s] += wv.x*sv.x + wv.y*sv.y + wv.z*sv.z + wv.w*sv.w;
      }
    }
    #pragma unroll
    for (int s = 0; s < 7; s++) acc[s] = waveSum(acc[s]);
    if (l == 0) {
      float bq = ipb[d];
      #pragma unroll
      for (int s = 0; s < 7; s++) q7[(long)s*DIM + d] = acc[s] + bq;
    }
  }
  gbar(bar, 0);

  // ===== P2: adinit (blocks 0..13) + uproj (512 blocks, float4) =====
  if (bid < 14) {
    const int hq = bid * 4 + w;
    if (hq < NHQ) {
      const int h = hq / 7, q = hq % 7;
      float acc = 0;
      for (int i = l; i < 512; i += 64)
        acc += q7[(long)q*DIM + h*512 + i] * ipb[DIM + h*512 + i];
      acc = waveSum(acc);
      if (l == 0) { Aarr[hq] = 0.f; D0arr[hq] = SCALE * acc; }
    }
  }
  {
    const int bx = bid & 3, h = (bid >> 2) & 7, c = bid >> 5;  // c in 0..15 (32 hd each)
    if (tid < 224) {
      int s = tid >> 5, hd = tid & 31;
      smem[tid] = q7[(long)s*DIM + h*512 + c*32 + hd];
    }
    __syncthreads();
    const int e0 = bx*1024 + tid*4;
    float4 acc[7];
    #pragma unroll
    for (int s = 0; s < 7; s++) { acc[s].x = 0; acc[s].y = 0; acc[s].z = 0; acc[s].w = 0; }
    #pragma unroll 4
    for (int hd = 0; hd < 32; hd++) {
      float4 wv = *(const float4*)(ipw + ((long)(DIM + h*512 + c*32 + hd))*DIM + e0);
      #pragma unroll
      for (int s = 0; s < 7; s++) {
        float qv = smem[s*32 + hd];
        acc[s].x += qv*wv.x; acc[s].y += qv*wv.y; acc[s].z += qv*wv.z; acc[s].w += qv*wv.w;
      }
    }
    #pragma unroll
    for (int s = 0; s < 7; s++)
      *(float4*)&upart[(long)((c*8 + h)*7 + s)*DIM + e0] = acc[s];
  }
  gbar(bar, 1);

  // ===== P3: ured (blocks 0..127): u = SCALE*sum_c upart; ugbf; A/D0 atomics =====
  if (bid < 128) {
    const int bx = bid & 15, h = bid >> 4;
    const int e = bx*256 + tid;
    float ge = lng[e], be = lnb[e];
    #pragma unroll
    for (int s = 0; s < 7; s++) {
      float u = 0;
      #pragma unroll
      for (int c = 0; c < 16; c++) u += upart[(long)((c*8 + h)*7 + s)*DIM + e];
      u *= SCALE;
      ugbf[(long)(h*7 + s)*DIM + e] = f2bf(u * ge);
      float pa = waveSum(u * ge);
      float pd = waveSum(u * be);
      if (l == 0) {
        atomicAdd(&Aarr[h*7 + s], pa);
        atomicAdd(&D0arr[h*7 + s], pd);
      }
    }
  }
  gbar(bar, 2);

  // ===== P4: scores2 (1024 virtual): raw scores + LN-stat partials, K split 4 =====
  for (int vb = bid; vb < 1024; vb += NBLKS) {
    const int lr = l & 15, lk8 = (l >> 4) * 8;
    const int rowblk = vb >> 2, ks = vb & 3;
    const int row0w = rowblk * 64 + w * 16;
    const long arow = (long)(row0w + lr) * DIM;
    const int kbase = ks * 1024;
    f32x4 acc0 = {0,0,0,0}, acc1 = {0,0,0,0}, acc2 = {0,0,0,0}, acc3 = {0,0,0,0};
    float sx = 0.f, sxx = 0.f;
    const long b0 = (long)(0*16 + lr)*DIM, b1 = (long)(1*16 + lr)*DIM,
               b2 = (long)(2*16 + lr)*DIM, b3 = (long)(3*16 + lr)*DIM;
    #pragma unroll 2
    for (int kc = kbase; kc < kbase + 1024; kc += 32) {
      const float4 v0 = *(const float4*)(x + arow + kc + lk8);
      const float4 v1 = *(const float4*)(x + arow + kc + lk8 + 4);
      sx  += (v0.x + v0.y) + (v0.z + v0.w) + (v1.x + v1.y) + (v1.z + v1.w);
      sxx += v0.x*v0.x + v0.y*v0.y + v0.z*v0.z + v0.w*v0.w
           + v1.x*v1.x + v1.y*v1.y + v1.z*v1.z + v1.w*v1.w;
      short8x a;
      a[0] = (short)f2bfr(v0.x); a[1] = (short)f2bfr(v0.y);
      a[2] = (short)f2bfr(v0.z); a[3] = (short)f2bfr(v0.w);
      a[4] = (short)f2bfr(v1.x); a[5] = (short)f2bfr(v1.y);
      a[6] = (short)f2bfr(v1.z); a[7] = (short)f2bfr(v1.w);
      short8x bb0 = *(const short8x*)(ugbf + b0 + kc + lk8);
      acc0 = __builtin_amdgcn_mfma_f32_16x16x32_bf16(a, bb0, acc0, 0, 0, 0);
      short8x bb1 = *(const short8x*)(ugbf + b1 + kc + lk8);
      acc1 = __builtin_amdgcn_mfma_f32_16x16x32_bf16(a, bb1, acc1, 0, 0, 0);
      short8x bb2 = *(const short8x*)(ugbf + b2 + kc + lk8);
      acc2 = __builtin_amdgcn_mfma_f32_16x16x32_bf16(a, bb2, acc2, 0, 0, 0);
      short8x bb3 = *(const short8x*)(ugbf + b3 + kc + lk8);
      acc3 = __builtin_amdgcn_mfma_f32_16x16x32_bf16(a, bb3, acc3, 0, 0, 0);
    }
    sx += __shfl_xor(sx, 16);  sx += __shfl_xor(sx, 32);
    sxx += __shfl_xor(sxx, 16); sxx += __shfl_xor(sxx, 32);
    if (l < 16) {
      float2 p; p.x = sx; p.y = sxx;
      statp[(long)ks*NROWS + row0w + l] = p;
    }
    const long base = ((long)ks*NROWS + row0w) * 64;
    #pragma unroll
    for (int i = 0; i < 4; i++) {
      long ro = base + (long)((l >> 4)*4 + i) * 64 + lr;
      raw[ro +  0] = acc0[i];
      raw[ro + 16] = acc1[i];
      raw[ro + 32] = acc2[i];
      raw[ro + 48] = acc3[i];
    }
  }
  gbar(bar, 3);

  // ===== P5: sepi (1024 virtual, 16 rows each): finalize LN, sct=exp, expsum atomics =====
  for (int vb = bid; vb < 1024; vb += NBLKS) {
    const int b = vb >> 7;
    float esum = 0.f;
    #pragma unroll
    for (int r4 = 0; r4 < 4; r4++) {
      const int row = vb*16 + w*4 + r4;
      float s = 0;
      #pragma unroll
      for (int ks = 0; ks < 4; ks++) s += raw[((long)ks*NROWS + row)*64 + l];
      float sx = 0, sxx = 0;
      #pragma unroll
      for (int ks = 0; ks < 4; ks++) {
        float2 p = statp[(long)ks*NROWS + row];
        sx += p.x; sxx += p.y;
      }
      float muv = sx * (1.0f/DIM), var = sxx * (1.0f/DIM) - muv*muv;
      float rs = rsqrtf(var + 1e-5f);
      if (l == 0) { mu[row] = muv; rstd[row] = rs; }
      if (l < NHQ) {
        float e = __expf(rs*(s - muv*Aarr[l]) + D0arr[l]);
        sct[(long)l*NROWS + row] = e;
        esum += e;
      }
    }
    __syncthreads();
    smem[w*64 + l] = esum;
    __syncthreads();
    if (w == 0 && l < NHQ) {
      float tot = smem[l] + smem[64 + l] + smem[128 + l] + smem[192 + l];
      atomicAdd(&sumexp[b*NHQ + l], tot);
    }
    __syncthreads();
  }
  gbar(bar, 4);

  // ===== P6: attnmeans (blocks 0..63): am, out_attn, s1 atomics =====
  if (bid < 64) {
    const int b = bid >> 3, nc = bid & 7;
    const int n = nc*256 + tid, row = b*NN + n;
    if (tid < NHQ) smem[tid] = 1.0f / sumexp[b*NHQ + tid];
    __syncthreads();
    const float mur = mu[row] * rstd[row];
    float aq[7] = {0,0,0,0,0,0,0};
    #pragma unroll
    for (int h = 0; h < 8; h++) {
      float ah = 0;
      #pragma unroll
      for (int q = 0; q < 7; q++) {
        float p = sct[(long)(h*7 + q)*NROWS + row] * smem[h*7 + q];
        aq[q] += p; ah += p;
      }
      float amv = ah * (1.0f/7.0f);
      am[((long)(b*8 + h))*NN + n] = amv;
      float sv = waveSum(amv * mur);
      if (l == 0) atomicAdd(&s1[b*8 + h], sv);
    }
    #pragma unroll
    for (int q = 0; q < 7; q++) out_attn[((long)(b*NQ + q))*NN + n] = aq[q] * 0.125f;
  }
  gbar(bar, 5);

  // ===== P7: ypart (512, 1:1): 16 n-chunks of 128 rows =====
  {
    const int b = bid >> 6, ec = (bid >> 4) & 3, nc = bid & 15;
    for (int i = tid; i < 1024; i += 256) {
      int h = i >> 7, nn = i & 127;
      int row = b*NN + nc*128 + nn;
      smem[h*128 + nn] = am[((long)(b*8 + h))*NN + nc*128 + nn] * rstd[row];
    }
    __syncthreads();
    const int e = ec*1024 + tid*4;
    float ax[8], ay[8], az[8], aw[8];
    #pragma unroll
    for (int h = 0; h < 8; h++) { ax[h]=0; ay[h]=0; az[h]=0; aw[h]=0; }
    const float* xp = x + ((long)(b*NN + nc*128))*DIM + e;
    #pragma unroll 2
    for (int nn = 0; nn < 128; nn++) {
      const float4 xv = *(const float4*)(xp + (long)nn*DIM);
      #pragma unroll
      for (int h = 0; h < 8; h++) {
        float a = smem[h*128 + nn];
        ax[h] += a*xv.x; ay[h] += a*xv.y; az[h] += a*xv.z; aw[h] += a*xv.w;
      }
    }
    #pragma unroll
    for (int h = 0; h < 8; h++) {
      float4 o; o.x = ax[h]; o.y = ay[h]; o.z = az[h]; o.w = aw[h];
      *(float4*)&part[((long)(nc*64 + b*8 + h))*DIM + e] = o;
    }
    __syncthreads();
  }
  gbar(bar, 6);

  // ===== P8: yred (262144 scalar, x2 loop): ym = lng*(sum part - s1) + lnb =====
  for (int it = 0; it < 2; it++) {
    const int i = it*131072 + bid*256 + tid;
    float s = 0;
    #pragma unroll
    for (int nc = 0; nc < 16; nc++) s += part[(long)nc*262144 + i];
    const int bh = i >> 12, e = i & 4095;
    ym[i] = lng[e]*(s - s1[bh]) + lnb[e];
  }
  gbar(bar, 7);

  // ===== P9: ctxm (1024 virtual) =====
  for (int vb = bid; vb < 1024; vb += NBLKS) {
    const int d = vb*4 + w;
    const int h = d >> 9;
    const float4* wr4 = (const float4*)(ipw + ((long)(2*DIM + d))*DIM);
    float acc[8] = {0,0,0,0,0,0,0,0};
    for (int e4 = l; e4 < 1024; e4 += 64) {
      float4 wv = wr4[e4];
      #pragma unroll
      for (int b = 0; b < 8; b++) {
        float4 y = ((const float4*)(ym + (long)(b*8 + h)*DIM))[e4];
        acc[b] += wv.x*y.x + wv.y*y.y + wv.z*y.z + wv.w*y.w;
      }
    }
    #pragma unroll
    for (int b = 0; b < 8; b++) acc[b] = waveSum(acc[b]);
    if (l == 0) {
      float bias = ipb[2*DIM + d];
      #pragma unroll
      for (int b = 0; b < 8; b++) ctxm[(long)b*DIM + d] = acc[b] + bias;
    }
  }
  gbar(bar, 8);

  // ===== P10: gvec (1024 virtual): gfin = tanh(alpha)*(sm + opw.ctxm + opb) =====
  for (int vb = bid; vb < 1024; vb += NBLKS) {
    const int d = vb*4 + w;
    const float4* wr4 = (const float4*)(opw + (long)d*DIM);
    float acc[8] = {0,0,0,0,0,0,0,0};
    for (int e4 = l; e4 < 1024; e4 += 64) {
      float4 wv = wr4[e4];
      #pragma unroll
      for (int b = 0; b < 8; b++) {
        float4 c = ((const float4*)(ctxm + (long)b*DIM))[e4];
        acc[b] += wv.x*c.x + wv.y*c.y + wv.z*c.z + wv.w*c.w;
      }
    }
    #pragma unroll
    for (int b = 0; b < 8; b++) acc[b] = waveSum(acc[b]);
    if (l == 0) {
      float smv = 0;
      #pragma unroll
      for (int q = 0; q < 7; q++)
        smv += fminf(fmaxf(slots[(long)q*DIM + d], -10.f), 10.f);
      smv *= (1.0f/7.0f);
      float t = tanhf(alpha[0]);
      float base = smv + opb[d];
      #pragma unroll
      for (int b = 0; b < 8; b++) gfin[(long)b*DIM + d] = t * (base + acc[b]);
    }
  }
}

// ---- final stream: x_refined = x + g[b]
__global__ __launch_bounds__(256) void k_refine(const float* __restrict__ x,
    const float* __restrict__ gfin, float* __restrict__ out) {
  const float4* x4 = (const float4*)x;
  const float4* g4 = (const float4*)gfin;
  float4* o4 = (float4*)out;
  const long total = (long)NROWS * 1024;
  for (long i4 = (long)blockIdx.x*256 + threadIdx.x; i4 < total; i4 += (long)gridDim.x*256) {
    long b = i4 >> 21;
    long e4 = i4 & 1023;
    float4 xv = x4[i4], gv = g4[b*1024 + e4];
    float4 o; o.x = xv.x + gv.x; o.y = xv.y + gv.y; o.z = xv.z + gv.z; o.w = xv.w + gv.w;
    o4[i4] = o;
  }
}

extern "C" void kernel_launch(void* const* d_in, const int* in_sizes, int n_in,
                              void* d_out, int out_size, void* d_ws, size_t ws_size,
                              hipStream_t stream) {
  const float* x     = (const float*)d_in[0];
  const float* slots = (const float*)d_in[1];
  const float* lng   = (const float*)d_in[2];
  const float* lnb   = (const float*)d_in[3];
  const float* ipw   = (const float*)d_in[4];
  const float* ipb   = (const float*)d_in[5];
  const float* opw   = (const float*)d_in[6];
  const float* opb   = (const float*)d_in[7];
  const float* alpha = (const float*)d_in[8];
  float* out = (float*)d_out;
  float* ws  = (float*)d_ws;

  // zero the grid-barrier counters (graph-legal async memset, every call)
  hipMemsetAsync((char*)d_ws + OFF_BAR*4, 0, 128, stream);

  hipLaunchKernelGGL(k_mega, dim3(NBLKS), dim3(256), 0, stream,
                     x, slots, lng, lnb, ipw, ipb, opw, opb, alpha, out, ws);
  hipLaunchKernelGGL(k_refine, dim3(8192), dim3(256), 0, stream,
                     x, ws + OFF_GFIN, out);
}

// Round 6
// 770.599 us; speedup vs baseline: 1.5533x; 1.5533x over previous
//
#include <hip/hip_runtime.h>

typedef __attribute__((ext_vector_type(4))) float f32x4;
typedef __attribute__((ext_vector_type(8))) short short8x;

#define DIM   4096
#define NB    8
#define NN    2048
#define NROWS (NB*NN)
#define NQ    7
#define NHQ   56
#define SCALE 0.04419417382415922f  /* 1/sqrt(512) */
#define NBLKS 512
#define NLEAF 16
#define BPL   (NBLKS/NLEAF)

// ---- workspace layout (float offsets), ~24.1 MB used
#define OFF_MU     0L          /* 16384 */
#define OFF_RSTD   16384L      /* 16384 */
#define OFF_Q7     32768L      /* 28672 */
#define OFF_A      61440L      /* 64 */
#define OFF_D0     61504L      /* 64 */
#define OFF_S1     61568L      /* 64 */
#define OFF_SUMEXP 61632L      /* 448 */
#define OFF_CTXM   62528L      /* 32768 */
#define OFF_GFIN   95296L      /* 32768 */
#define OFF_YM     128064L     /* 262144 */
#define OFF_UGBF   390208L     /* 64*4096 ushorts = 131072 floats */
#define OFF_STATP  521280L     /* 4*16384 float2 = 131072 */
#define OFF_SCT    652352L     /* 56*16384 = 917504 used (ends 1569856) */
#define OFF_BAR    1600000L    /* 1152 uints = 4608 B barrier block */
#define OFF_BIG    1700928L    /* time-shared: upart 16*56*4096=3670016 ;
                                  raw 4*16384*64=4194304 ;
                                  am 131072 @+0, part 16*64*4096=4194304 @+131072 */
#define OFF_AM     (OFF_BIG)
#define OFF_PART   (OFF_BIG + 131072L)

// barrier layout (uint indices within bar):
//   [0]            gen (release counter, 16 spinners)
//   [32]           root arrive counter
//   [64  + i*32]   leaf arrive counter i   (i < 16)
//   [576 + i*32]   leaf release word i     (31 spinners each, private line)

__device__ __forceinline__ unsigned short f2bf(float f) {   // RNE
  union { float f; unsigned int u; } v; v.f = f;
  return (unsigned short)((v.u + 0x7FFFu + ((v.u >> 16) & 1u)) >> 16);
}
__device__ __forceinline__ unsigned short f2bfr(float f) {  // cheap round
  union { float f; unsigned int u; } v; v.f = f;
  return (unsigned short)((v.u + 0x8000u) >> 16);
}
__device__ __forceinline__ float waveSum(float v) {
  #pragma unroll
  for (int m = 1; m < 64; m <<= 1) v += __shfl_xor(v, m);
  return v;
}

// monotonic tree barrier, distributed spin lines, ~1us backoff
__device__ __forceinline__ void gbar(unsigned* bar, int k) {
  __syncthreads();
  if (threadIdx.x == 0) {
    const int li = blockIdx.x & (NLEAF - 1);
    unsigned* leaf = bar + 64 + li*32;
    unsigned* lrel = bar + 576 + li*32;
    __threadfence();  // release all prior writes
    unsigned a = __hip_atomic_fetch_add(leaf, 1u, __ATOMIC_ACQ_REL, __HIP_MEMORY_SCOPE_AGENT);
    if (a == (unsigned)((k + 1) * BPL - 1)) {
      // leaf master
      unsigned r = __hip_atomic_fetch_add(bar + 32, 1u, __ATOMIC_ACQ_REL, __HIP_MEMORY_SCOPE_AGENT);
      if (r == (unsigned)((k + 1) * NLEAF - 1))
        __hip_atomic_fetch_add(bar, 1u, __ATOMIC_ACQ_REL, __HIP_MEMORY_SCOPE_AGENT);
      while (__hip_atomic_load(bar, __ATOMIC_RELAXED, __HIP_MEMORY_SCOPE_AGENT) < (unsigned)(k + 1))
        __builtin_amdgcn_s_sleep(32);
      __hip_atomic_store(lrel, (unsigned)(k + 1), __ATOMIC_RELEASE, __HIP_MEMORY_SCOPE_AGENT);
    } else {
      while (__hip_atomic_load(lrel, __ATOMIC_RELAXED, __HIP_MEMORY_SCOPE_AGENT) < (unsigned)(k + 1))
        __builtin_amdgcn_s_sleep(32);
    }
    __threadfence();  // acquire side
  }
  __syncthreads();
}

__global__ __launch_bounds__(256, 4) void k_mega(
    const float* __restrict__ x, const float* __restrict__ slots,
    const float* __restrict__ lng, const float* __restrict__ lnb,
    const float* __restrict__ ipw, const float* __restrict__ ipb,
    const float* __restrict__ opw, const float* __restrict__ opb,
    const float* __restrict__ alpha, float* __restrict__ out, float* __restrict__ ws) {
  __shared__ float smem[1024];
  const int bid = blockIdx.x, tid = threadIdx.x;
  const int w = tid >> 6, l = tid & 63;

  float* mu     = ws + OFF_MU;
  float* rstd   = ws + OFF_RSTD;
  float* q7     = ws + OFF_Q7;
  float* Aarr   = ws + OFF_A;
  float* D0arr  = ws + OFF_D0;
  float* s1     = ws + OFF_S1;
  float* sumexp = ws + OFF_SUMEXP;
  float* ctxm   = ws + OFF_CTXM;
  float* gfin   = ws + OFF_GFIN;
  float* ym     = ws + OFF_YM;
  unsigned short* ugbf = (unsigned short*)(ws + OFF_UGBF);
  float2* statp = (float2*)(ws + OFF_STATP);
  float* sct    = ws + OFF_SCT;
  unsigned* bar = (unsigned*)(ws + OFF_BAR);
  float* upart  = ws + OFF_BIG;
  float* raw    = ws + OFF_BIG;
  float* am     = ws + OFF_AM;
  float* part   = ws + OFF_PART;
  float* out_attn = out + (long)NROWS * DIM;

  // ===== P1: qproj (1024 virtual) + zero sumexp/s1 + zero ugbf pad rows =====
  if (bid == 0) {
    if (tid < 448) sumexp[tid] = 0.f;
    else if (tid < 512) s1[tid - 448] = 0.f;
  } else if (bid <= 8) {  // pad row 56+bid-1
    unsigned* u32 = (unsigned*)ugbf;
    const long r = 56 + bid - 1;
    #pragma unroll
    for (int j = 0; j < 8; j++) u32[r*2048 + (long)tid*8 + j] = 0u;
  }
  for (int vb = bid; vb < 1024; vb += NBLKS) {
    const int d = vb * 4 + w;
    const float4* wr4 = (const float4*)(ipw + (long)d * DIM);
    float acc[7] = {0,0,0,0,0,0,0};
    for (int e4 = l; e4 < 1024; e4 += 64) {
      float4 wv = wr4[e4];
      #pragma unroll
      for (int s = 0; s < 7; s++) {
        float4 sv = ((const float4*)(slots + (long)s*DIM))[e4];
        sv.x = fminf(fmaxf(sv.x, -10.f), 10.f); sv.y = fminf(fmaxf(sv.y, -10.f), 10.f);
        sv.z = fminf(fmaxf(sv.z, -10.f), 10.f); sv.w = fminf(fmaxf(sv.w, -10.f), 10.f);
        acc[s] += wv.x*sv.x + wv.y*sv.y + wv.z*sv.z + wv.w*sv.w;
      }
    }
    #pragma unroll
    for (int s = 0; s < 7; s++) acc[s] = waveSum(acc[s]);
    if (l == 0) {
      float bq = ipb[d];
      #pragma unroll
      for (int s = 0; s < 7; s++) q7[(long)s*DIM + d] = acc[s] + bq;
    }
  }
  gbar(bar, 0);

  // ===== P2: adinit (blocks 0..13) + uproj (512 blocks, float4) =====
  if (bid < 14) {
    const int hq = bid * 4 + w;
    if (hq < NHQ) {
      const int h = hq / 7, q = hq % 7;
      float acc = 0;
      for (int i = l; i < 512; i += 64)
        acc += q7[(long)q*DIM + h*512 + i] * ipb[DIM + h*512 + i];
      acc = waveSum(acc);
      if (l == 0) { Aarr[hq] = 0.f; D0arr[hq] = SCALE * acc; }
    }
  }
  {
    const int bx = bid & 3, h = (bid >> 2) & 7, c = bid >> 5;  // c in 0..15 (32 hd each)
    if (tid < 224) {
      int s = tid >> 5, hd = tid & 31;
      smem[tid] = q7[(long)s*DIM + h*512 + c*32 + hd];
    }
    __syncthreads();
    const int e0 = bx*1024 + tid*4;
    float4 acc[7];
    #pragma unroll
    for (int s = 0; s < 7; s++) { acc[s].x = 0; acc[s].y = 0; acc[s].z = 0; acc[s].w = 0; }
    #pragma unroll 4
    for (int hd = 0; hd < 32; hd++) {
      float4 wv = *(const float4*)(ipw + ((long)(DIM + h*512 + c*32 + hd))*DIM + e0);
      #pragma unroll
      for (int s = 0; s < 7; s++) {
        float qv = smem[s*32 + hd];
        acc[s].x += qv*wv.x; acc[s].y += qv*wv.y; acc[s].z += qv*wv.z; acc[s].w += qv*wv.w;
      }
    }
    #pragma unroll
    for (int s = 0; s < 7; s++)
      *(float4*)&upart[(long)((c*8 + h)*7 + s)*DIM + e0] = acc[s];
  }
  gbar(bar, 1);

  // ===== P3: ured (blocks 0..127): u = SCALE*sum_c upart; ugbf; A/D0 atomics =====
  if (bid < 128) {
    const int bx = bid & 15, h = bid >> 4;
    const int e = bx*256 + tid;
    float ge = lng[e], be = lnb[e];
    #pragma unroll
    for (int s = 0; s < 7; s++) {
      float u = 0;
      #pragma unroll
      for (int c = 0; c < 16; c++) u += upart[(long)((c*8 + h)*7 + s)*DIM + e];
      u *= SCALE;
      ugbf[(long)(h*7 + s)*DIM + e] = f2bf(u * ge);
      float pa = waveSum(u * ge);
      float pd = waveSum(u * be);
      if (l == 0) {
        atomicAdd(&Aarr[h*7 + s], pa);
        atomicAdd(&D0arr[h*7 + s], pd);
      }
    }
  }
  gbar(bar, 2);

  // ===== P4: scores2 (1024 virtual): raw scores + LN-stat partials, K split 4 =====
  for (int vb = bid; vb < 1024; vb += NBLKS) {
    const int lr = l & 15, lk8 = (l >> 4) * 8;
    const int rowblk = vb >> 2, ks = vb & 3;
    const int row0w = rowblk * 64 + w * 16;
    const long arow = (long)(row0w + lr) * DIM;
    const int kbase = ks * 1024;
    f32x4 acc0 = {0,0,0,0}, acc1 = {0,0,0,0}, acc2 = {0,0,0,0}, acc3 = {0,0,0,0};
    float sx = 0.f, sxx = 0.f;
    const long b0 = (long)(0*16 + lr)*DIM, b1 = (long)(1*16 + lr)*DIM,
               b2 = (long)(2*16 + lr)*DIM, b3 = (long)(3*16 + lr)*DIM;
    #pragma unroll 2
    for (int kc = kbase; kc < kbase + 1024; kc += 32) {
      const float4 v0 = *(const float4*)(x + arow + kc + lk8);
      const float4 v1 = *(const float4*)(x + arow + kc + lk8 + 4);
      sx  += (v0.x + v0.y) + (v0.z + v0.w) + (v1.x + v1.y) + (v1.z + v1.w);
      sxx += v0.x*v0.x + v0.y*v0.y + v0.z*v0.z + v0.w*v0.w
           + v1.x*v1.x + v1.y*v1.y + v1.z*v1.z + v1.w*v1.w;
      short8x a;
      a[0] = (short)f2bfr(v0.x); a[1] = (short)f2bfr(v0.y);
      a[2] = (short)f2bfr(v0.z); a[3] = (short)f2bfr(v0.w);
      a[4] = (short)f2bfr(v1.x); a[5] = (short)f2bfr(v1.y);
      a[6] = (short)f2bfr(v1.z); a[7] = (short)f2bfr(v1.w);
      short8x bb0 = *(const short8x*)(ugbf + b0 + kc + lk8);
      acc0 = __builtin_amdgcn_mfma_f32_16x16x32_bf16(a, bb0, acc0, 0, 0, 0);
      short8x bb1 = *(const short8x*)(ugbf + b1 + kc + lk8);
      acc1 = __builtin_amdgcn_mfma_f32_16x16x32_bf16(a, bb1, acc1, 0, 0, 0);
      short8x bb2 = *(const short8x*)(ugbf + b2 + kc + lk8);
      acc2 = __builtin_amdgcn_mfma_f32_16x16x32_bf16(a, bb2, acc2, 0, 0, 0);
      short8x bb3 = *(const short8x*)(ugbf + b3 + kc + lk8);
      acc3 = __builtin_amdgcn_mfma_f32_16x16x32_bf16(a, bb3, acc3, 0, 0, 0);
    }
    sx += __shfl_xor(sx, 16);  sx += __shfl_xor(sx, 32);
    sxx += __shfl_xor(sxx, 16); sxx += __shfl_xor(sxx, 32);
    if (l < 16) {
      float2 p; p.x = sx; p.y = sxx;
      statp[(long)ks*NROWS + row0w + l] = p;
    }
    const long base = ((long)ks*NROWS + row0w) * 64;
    #pragma unroll
    for (int i = 0; i < 4; i++) {
      long ro = base + (long)((l >> 4)*4 + i) * 64 + lr;
      raw[ro +  0] = acc0[i];
      raw[ro + 16] = acc1[i];
      raw[ro + 32] = acc2[i];
      raw[ro + 48] = acc3[i];
    }
  }
  gbar(bar, 3);

  // ===== P5: sepi (1024 virtual, 16 rows each): finalize LN, sct=exp, expsum atomics =====
  for (int vb = bid; vb < 1024; vb += NBLKS) {
    const int b = vb >> 7;
    float esum = 0.f;
    #pragma unroll
    for (int r4 = 0; r4 < 4; r4++) {
      const int row = vb*16 + w*4 + r4;
      float s = 0;
      #pragma unroll
      for (int ks = 0; ks < 4; ks++) s += raw[((long)ks*NROWS + row)*64 + l];
      float sx = 0, sxx = 0;
      #pragma unroll
      for (int ks = 0; ks < 4; ks++) {
        float2 p = statp[(long)ks*NROWS + row];
        sx += p.x; sxx += p.y;
      }
      float muv = sx * (1.0f/DIM), var = sxx * (1.0f/DIM) - muv*muv;
      float rs = rsqrtf(var + 1e-5f);
      if (l == 0) { mu[row] = muv; rstd[row] = rs; }
      if (l < NHQ) {
        float e = __expf(rs*(s - muv*Aarr[l]) + D0arr[l]);
        sct[(long)l*NROWS + row] = e;
        esum += e;
      }
    }
    __syncthreads();
    smem[w*64 + l] = esum;
    __syncthreads();
    if (w == 0 && l < NHQ) {
      float tot = smem[l] + smem[64 + l] + smem[128 + l] + smem[192 + l];
      atomicAdd(&sumexp[b*NHQ + l], tot);
    }
    __syncthreads();
  }
  gbar(bar, 4);

  // ===== P6: attnmeans (blocks 0..63): am, out_attn, s1 atomics =====
  if (bid < 64) {
    const int b = bid >> 3, nc = bid & 7;
    const int n = nc*256 + tid, row = b*NN + n;
    if (tid < NHQ) smem[tid] = 1.0f / sumexp[b*NHQ + tid];
    __syncthreads();
    const float mur = mu[row] * rstd[row];
    float aq[7] = {0,0,0,0,0,0,0};
    #pragma unroll
    for (int h = 0; h < 8; h++) {
      float ah = 0;
      #pragma unroll
      for (int q = 0; q < 7; q++) {
        float p = sct[(long)(h*7 + q)*NROWS + row] * smem[h*7 + q];
        aq[q] += p; ah += p;
      }
      float amv = ah * (1.0f/7.0f);
      am[((long)(b*8 + h))*NN + n] = amv;
      float sv = waveSum(amv * mur);
      if (l == 0) atomicAdd(&s1[b*8 + h], sv);
    }
    #pragma unroll
    for (int q = 0; q < 7; q++) out_attn[((long)(b*NQ + q))*NN + n] = aq[q] * 0.125f;
  }
  gbar(bar, 5);

  // ===== P7: ypart (512, 1:1): 16 n-chunks of 128 rows =====
  {
    const int b = bid >> 6, ec = (bid >> 4) & 3, nc = bid & 15;
    for (int i = tid; i < 1024; i += 256) {
      int h = i >> 7, nn = i & 127;
      int row = b*NN + nc*128 + nn;
      smem[h*128 + nn] = am[((long)(b*8 + h))*NN + nc*128 + nn] * rstd[row];
    }
    __syncthreads();
    const int e = ec*1024 + tid*4;
    float ax[8], ay[8], az[8], aw[8];
    #pragma unroll
    for (int h = 0; h < 8; h++) { ax[h]=0; ay[h]=0; az[h]=0; aw[h]=0; }
    const float* xp = x + ((long)(b*NN + nc*128))*DIM + e;
    #pragma unroll 2
    for (int nn = 0; nn < 128; nn++) {
      const float4 xv = *(const float4*)(xp + (long)nn*DIM);
      #pragma unroll
      for (int h = 0; h < 8; h++) {
        float a = smem[h*128 + nn];
        ax[h] += a*xv.x; ay[h] += a*xv.y; az[h] += a*xv.z; aw[h] += a*xv.w;
      }
    }
    #pragma unroll
    for (int h = 0; h < 8; h++) {
      float4 o; o.x = ax[h]; o.y = ay[h]; o.z = az[h]; o.w = aw[h];
      *(float4*)&part[((long)(nc*64 + b*8 + h))*DIM + e] = o;
    }
    __syncthreads();
  }
  gbar(bar, 6);

  // ===== P8: yred (262144 scalar, x2 loop): ym = lng*(sum part - s1) + lnb =====
  for (int it = 0; it < 2; it++) {
    const int i = it*131072 + bid*256 + tid;
    float s = 0;
    #pragma unroll
    for (int nc = 0; nc < 16; nc++) s += part[(long)nc*262144 + i];
    const int bh = i >> 12, e = i & 4095;
    ym[i] = lng[e]*(s - s1[bh]) + lnb[e];
  }
  gbar(bar, 7);

  // ===== P9: ctxm (1024 virtual) =====
  for (int vb = bid; vb < 1024; vb += NBLKS) {
    const int d = vb*4 + w;
    const int h = d >> 9;
    const float4* wr4 = (const float4*)(ipw + ((long)(2*DIM + d))*DIM);
    float acc[8] = {0,0,0,0,0,0,0,0};
    for (int e4 = l; e4 < 1024; e4 += 64) {
      float4 wv = wr4[e4];
      #pragma unroll
      for (int b = 0; b < 8; b++) {
        float4 y = ((const float4*)(ym + (long)(b*8 + h)*DIM))[e4];
        acc[b] += wv.x*y.x + wv.y*y.y + wv.z*y.z + wv.w*y.w;
      }
    }
    #pragma unroll
    for (int b = 0; b < 8; b++) acc[b] = waveSum(acc[b]);
    if (l == 0) {
      float bias = ipb[2*DIM + d];
      #pragma unroll
      for (int b = 0; b < 8; b++) ctxm[(long)b*DIM + d] = acc[b] + bias;
    }
  }
  gbar(bar, 8);

  // ===== P10: gvec (1024 virtual): gfin = tanh(alpha)*(sm + opw.ctxm + opb) =====
  for (int vb = bid; vb < 1024; vb += NBLKS) {
    const int d = vb*4 + w;
    const float4* wr4 = (const float4*)(opw + (long)d*DIM);
    float acc[8] = {0,0,0,0,0,0,0,0};
    for (int e4 = l; e4 < 1024; e4 += 64) {
      float4 wv = wr4[e4];
      #pragma unroll
      for (int b = 0; b < 8; b++) {
        float4 c = ((const float4*)(ctxm + (long)b*DIM))[e4];
        acc[b] += wv.x*c.x + wv.y*c.y + wv.z*c.z + wv.w*c.w;
      }
    }
    #pragma unroll
    for (int b = 0; b < 8; b++) acc[b] = waveSum(acc[b]);
    if (l == 0) {
      float smv = 0;
      #pragma unroll
      for (int q = 0; q < 7; q++)
        smv += fminf(fmaxf(slots[(long)q*DIM + d], -10.f), 10.f);
      smv *= (1.0f/7.0f);
      float t = tanhf(alpha[0]);
      float base = smv + opb[d];
      #pragma unroll
      for (int b = 0; b < 8; b++) gfin[(long)b*DIM + d] = t * (base + acc[b]);
    }
  }
}

// ---- final stream: x_refined = x + g[b]
__global__ __launch_bounds__(256) void k_refine(const float* __restrict__ x,
    const float* __restrict__ gfin, float* __restrict__ out) {
  const float4* x4 = (const float4*)x;
  const float4* g4 = (const float4*)gfin;
  float4* o4 = (float4*)out;
  const long total = (long)NROWS * 1024;
  for (long i4 = (long)blockIdx.x*256 + threadIdx.x; i4 < total; i4 += (long)gridDim.x*256) {
    long b = i4 >> 21;
    long e4 = i4 & 1023;
    float4 xv = x4[i4], gv = g4[b*1024 + e4];
    float4 o; o.x = xv.x + gv.x; o.y = xv.y + gv.y; o.z = xv.z + gv.z; o.w = xv.w + gv.w;
    o4[i4] = o;
  }
}

extern "C" void kernel_launch(void* const* d_in, const int* in_sizes, int n_in,
                              void* d_out, int out_size, void* d_ws, size_t ws_size,
                              hipStream_t stream) {
  const float* x     = (const float*)d_in[0];
  const float* slots = (const float*)d_in[1];
  const float* lng   = (const float*)d_in[2];
  const float* lnb   = (const float*)d_in[3];
  const float* ipw   = (const float*)d_in[4];
  const float* ipb   = (const float*)d_in[5];
  const float* opw   = (const float*)d_in[6];
  const float* opb   = (const float*)d_in[7];
  const float* alpha = (const float*)d_in[8];
  float* out = (float*)d_out;
  float* ws  = (float*)d_ws;

  // zero the grid-barrier block (graph-legal async memset, every call)
  hipMemsetAsync((char*)d_ws + OFF_BAR*4, 0, 4608, stream);

  hipLaunchKernelGGL(k_mega, dim3(NBLKS), dim3(256), 0, stream,
                     x, slots, lng, lnb, ipw, ipb, opw, opb, alpha, out, ws);
  hipLaunchKernelGGL(k_refine, dim3(8192), dim3(256), 0, stream,
                     x, ws + OFF_GFIN, out);
}

// Round 7
// 400.988 us; speedup vs baseline: 2.9850x; 1.9218x over previous
//
#include <hip/hip_runtime.h>

typedef __attribute__((ext_vector_type(4))) float f32x4;
typedef __attribute__((ext_vector_type(8))) short short8x;

#define DIM   4096
#define NB    8
#define NN    2048
#define NROWS (NB*NN)
#define NQ    7
#define NHQ   56
#define SCALE 0.04419417382415922f  /* 1/sqrt(512) */

// ---- workspace layout (float offsets)
#define OFF_MU     0L          /* 16384 */
#define OFF_RSTD   16384L      /* 16384 */
#define OFF_Q7     32768L      /* 28672 */
#define OFF_A      61440L      /* 64 */
#define OFF_D0     61504L      /* 64 */
#define OFF_S1     61568L      /* 64 */
#define OFF_SUMEXP 61632L      /* 448 (+pad) */
#define OFF_CTXM   62528L      /* 32768 */
#define OFF_GFIN   95296L      /* 32768 */
#define OFF_YM     128064L     /* 262144 */
#define OFF_UGBF   390208L     /* 64*4096 ushorts = 131072 floats */
#define OFF_SCT    521280L     /* 56*16384 = 917504 */
#define OFF_BIG    1438784L    /* time-shared: upart 16*56*4096=3670016 ;
                                  part 16*64*4096=4194304 */
#define OFF_PART   (OFF_BIG)

__device__ __forceinline__ unsigned short f2bf(float f) {   // RNE
  union { float f; unsigned int u; } v; v.f = f;
  return (unsigned short)((v.u + 0x7FFFu + ((v.u >> 16) & 1u)) >> 16);
}
__device__ __forceinline__ unsigned short f2bfr(float f) {  // cheap round
  union { float f; unsigned int u; } v; v.f = f;
  return (unsigned short)((v.u + 0x8000u) >> 16);
}
__device__ __forceinline__ float waveSum(float v) {
  #pragma unroll
  for (int m = 1; m < 64; m <<= 1) v += __shfl_xor(v, m);
  return v;
}

// ---- K1: qproj (+ zero sumexp/s1/A/D0 and ugbf pad rows)
__global__ __launch_bounds__(256) void k_pre(const float* __restrict__ ipw,
    const float* __restrict__ ipb, const float* __restrict__ slots,
    float* __restrict__ q7, float* __restrict__ ws) {
  const int bid = blockIdx.x, tid = threadIdx.x;
  const int w = tid >> 6, l = tid & 63;
  if (bid == 0) {
    if (tid < 448) (ws + OFF_SUMEXP)[tid] = 0.f;
    else if (tid < 512) (ws + OFF_S1)[tid - 448] = 0.f;
  } else if (bid <= 8) {  // zero ugbf pad row 56+bid-1
    unsigned* u32 = (unsigned*)(ws + OFF_UGBF);
    const long r = 56 + bid - 1;
    #pragma unroll
    for (int j = 0; j < 8; j++) u32[r*2048 + (long)tid*8 + j] = 0u;
  } else if (bid == 9) {
    if (tid < 64) (ws + OFF_A)[tid] = 0.f;
    else if (tid < 128) (ws + OFF_D0)[tid - 64] = 0.f;
  }
  const int d = bid * 4 + w;
  const float4* wr4 = (const float4*)(ipw + (long)d * DIM);
  float acc[7] = {0,0,0,0,0,0,0};
  for (int e4 = l; e4 < 1024; e4 += 64) {
    float4 wv = wr4[e4];
    #pragma unroll
    for (int s = 0; s < 7; s++) {
      float4 sv = ((const float4*)(slots + (long)s*DIM))[e4];
      sv.x = fminf(fmaxf(sv.x, -10.f), 10.f); sv.y = fminf(fmaxf(sv.y, -10.f), 10.f);
      sv.z = fminf(fmaxf(sv.z, -10.f), 10.f); sv.w = fminf(fmaxf(sv.w, -10.f), 10.f);
      acc[s] += wv.x*sv.x + wv.y*sv.y + wv.z*sv.z + wv.w*sv.w;
    }
  }
  #pragma unroll
  for (int s = 0; s < 7; s++) acc[s] = waveSum(acc[s]);
  if (l == 0) {
    float bq = ipb[d];
    #pragma unroll
    for (int s = 0; s < 7; s++) q7[(long)s*DIM + d] = acc[s] + bq;
  }
}

// ---- K2: uproj partials + D0 bk-term atomics (bx==0 blocks)
__global__ __launch_bounds__(256) void k_uproj(const float* __restrict__ ipw,
    const float* __restrict__ ipb, const float* __restrict__ q7,
    float* __restrict__ upart, float* __restrict__ D0arr) {
  __shared__ float qs[7][32];
  const int bid = blockIdx.x, tid = threadIdx.x;
  const int bx = bid & 3, h = (bid >> 2) & 7, c = bid >> 5;  // c in 0..15
  if (tid < 224) {
    int s = tid >> 5, hd = tid & 31;
    qs[s][hd] = q7[(long)s*DIM + h*512 + c*32 + hd];
  }
  __syncthreads();
  if (bx == 0 && tid < 64) {  // D0 += SCALE * q.bk over this 32-hd chunk
    const int l = tid;
    float bk = (l < 32) ? ipb[DIM + h*512 + c*32 + l] : 0.f;
    #pragma unroll
    for (int s = 0; s < 7; s++) {
      float v = (l < 32) ? qs[s][l]*bk : 0.f;
      v = waveSum(v);
      if (l == 0) atomicAdd(&D0arr[h*7 + s], SCALE * v);
    }
  }
  const int e0 = bx*1024 + tid*4;
  float4 acc[7];
  #pragma unroll
  for (int s = 0; s < 7; s++) { acc[s].x = 0; acc[s].y = 0; acc[s].z = 0; acc[s].w = 0; }
  #pragma unroll 4
  for (int hd = 0; hd < 32; hd++) {
    float4 wv = *(const float4*)(ipw + ((long)(DIM + h*512 + c*32 + hd))*DIM + e0);
    #pragma unroll
    for (int s = 0; s < 7; s++) {
      float qv = qs[s][hd];
      acc[s].x += qv*wv.x; acc[s].y += qv*wv.y; acc[s].z += qv*wv.z; acc[s].w += qv*wv.w;
    }
  }
  #pragma unroll
  for (int s = 0; s < 7; s++)
    *(float4*)&upart[(long)((c*8 + h)*7 + s)*DIM + e0] = acc[s];
}

// ---- K3: u = SCALE*sum_c upart; ugbf = bf16(u*ln_g); A/D0 atomics
__global__ __launch_bounds__(256) void k_ured(const float* __restrict__ upart,
    const float* __restrict__ lng, const float* __restrict__ lnb,
    unsigned short* __restrict__ ugbf, float* __restrict__ Aarr, float* __restrict__ D0arr) {
  const int bid = blockIdx.x, tid = threadIdx.x;
  const int bx = bid & 15, h = bid >> 4;
  const int e = bx*256 + tid, l = tid & 63;
  float ge = lng[e], be = lnb[e];
  #pragma unroll
  for (int s = 0; s < 7; s++) {
    float u = 0;
    #pragma unroll
    for (int c = 0; c < 16; c++) u += upart[(long)((c*8 + h)*7 + s)*DIM + e];
    u *= SCALE;
    ugbf[(long)(h*7 + s)*DIM + e] = f2bf(u * ge);
    float pa = waveSum(u * ge);
    float pd = waveSum(u * be);
    if (l == 0) {
      atomicAdd(&Aarr[h*7 + s], pa);
      atomicAdd(&D0arr[h*7 + s], pd);
    }
  }
}

// ---- K4: full-K scores: LN stats + MFMA + epilogue exp + sumexp atomics
// grid 512 x 128 threads (2 waves x 16 rows)
__global__ __launch_bounds__(128) void k_scores(const float* __restrict__ x,
    const unsigned short* __restrict__ ugbf, const float* __restrict__ Aarr,
    const float* __restrict__ D0arr, float* __restrict__ mu_o, float* __restrict__ rstd_o,
    float* __restrict__ sct, float* __restrict__ sumexp) {
  const int tid = threadIdx.x;
  const int wid = tid >> 6, l = tid & 63;
  const int lr = l & 15, lk8 = (l >> 4) * 8;
  const int row0w = blockIdx.x * 32 + wid * 16;
  const int b = blockIdx.x >> 6;
  const long arow = (long)(row0w + lr) * DIM;
  f32x4 acc0 = {0,0,0,0}, acc1 = {0,0,0,0}, acc2 = {0,0,0,0}, acc3 = {0,0,0,0};
  float sx = 0.f, sxx = 0.f;
  const long b0 = (long)(0*16 + lr)*DIM, b1 = (long)(1*16 + lr)*DIM,
             b2 = (long)(2*16 + lr)*DIM, b3 = (long)(3*16 + lr)*DIM;
  #pragma unroll 2
  for (int kc = 0; kc < DIM; kc += 32) {
    const float4 v0 = *(const float4*)(x + arow + kc + lk8);
    const float4 v1 = *(const float4*)(x + arow + kc + lk8 + 4);
    sx  += (v0.x + v0.y) + (v0.z + v0.w) + (v1.x + v1.y) + (v1.z + v1.w);
    sxx += v0.x*v0.x + v0.y*v0.y + v0.z*v0.z + v0.w*v0.w
         + v1.x*v1.x + v1.y*v1.y + v1.z*v1.z + v1.w*v1.w;
    short8x a;
    a[0] = (short)f2bfr(v0.x); a[1] = (short)f2bfr(v0.y);
    a[2] = (short)f2bfr(v0.z); a[3] = (short)f2bfr(v0.w);
    a[4] = (short)f2bfr(v1.x); a[5] = (short)f2bfr(v1.y);
    a[6] = (short)f2bfr(v1.z); a[7] = (short)f2bfr(v1.w);
    short8x bb0 = *(const short8x*)(ugbf + b0 + kc + lk8);
    acc0 = __builtin_amdgcn_mfma_f32_16x16x32_bf16(a, bb0, acc0, 0, 0, 0);
    short8x bb1 = *(const short8x*)(ugbf + b1 + kc + lk8);
    acc1 = __builtin_amdgcn_mfma_f32_16x16x32_bf16(a, bb1, acc1, 0, 0, 0);
    short8x bb2 = *(const short8x*)(ugbf + b2 + kc + lk8);
    acc2 = __builtin_amdgcn_mfma_f32_16x16x32_bf16(a, bb2, acc2, 0, 0, 0);
    short8x bb3 = *(const short8x*)(ugbf + b3 + kc + lk8);
    acc3 = __builtin_amdgcn_mfma_f32_16x16x32_bf16(a, bb3, acc3, 0, 0, 0);
  }
  // finish LN stats: lanes {lr, lr+16, lr+32, lr+48} sum to full row lr
  sx += __shfl_xor(sx, 16);  sx += __shfl_xor(sx, 32);
  sxx += __shfl_xor(sxx, 16); sxx += __shfl_xor(sxx, 32);
  float muv = sx * (1.0f/DIM);
  float var = sxx * (1.0f/DIM) - muv*muv;
  float rsv = rsqrtf(var + 1e-5f);
  if (l < 16) { mu_o[row0w + l] = muv; rstd_o[row0w + l] = rsv; }
  // epilogue: lane holds C rows rl=(l>>4)*4+i, col hq=t*16+lr
  float es0 = 0, es1 = 0, es2 = 0, es3 = 0;
  #pragma unroll
  for (int i = 0; i < 4; i++) {
    const int rl = (l >> 4)*4 + i;
    const float mur_ = __shfl(muv, rl);
    const float rs_  = __shfl(rsv, rl);
    {
      int hq = 0*16 + lr; float Ah = Aarr[hq], Dh = D0arr[hq];
      float e = __expf(rs_*(acc0[i] - mur_*Ah) + Dh);
      sct[(long)hq*NROWS + row0w + rl] = e; es0 += e;
    }
    {
      int hq = 1*16 + lr; float Ah = Aarr[hq], Dh = D0arr[hq];
      float e = __expf(rs_*(acc1[i] - mur_*Ah) + Dh);
      sct[(long)hq*NROWS + row0w + rl] = e; es1 += e;
    }
    {
      int hq = 2*16 + lr; float Ah = Aarr[hq], Dh = D0arr[hq];
      float e = __expf(rs_*(acc2[i] - mur_*Ah) + Dh);
      sct[(long)hq*NROWS + row0w + rl] = e; es2 += e;
    }
    if (lr < 8) {
      int hq = 3*16 + lr; float Ah = Aarr[hq], Dh = D0arr[hq];
      float e = __expf(rs_*(acc3[i] - mur_*Ah) + Dh);
      sct[(long)hq*NROWS + row0w + rl] = e; es3 += e;
    }
  }
  es0 += __shfl_xor(es0, 16); es0 += __shfl_xor(es0, 32);
  es1 += __shfl_xor(es1, 16); es1 += __shfl_xor(es1, 32);
  es2 += __shfl_xor(es2, 16); es2 += __shfl_xor(es2, 32);
  es3 += __shfl_xor(es3, 16); es3 += __shfl_xor(es3, 32);
  if (l < 16) {
    atomicAdd(&sumexp[b*NHQ + 0*16 + l], es0);
    atomicAdd(&sumexp[b*NHQ + 1*16 + l], es1);
    atomicAdd(&sumexp[b*NHQ + 2*16 + l], es2);
    if (l < 8) atomicAdd(&sumexp[b*NHQ + 3*16 + l], es3);
  }
}

// ---- K5: ypart with inline am recompute; ec==0 also emits out_attn + s1
// grid 512: b(8) x ec(4) x nc(16); 128 rows per (b,nc)
__global__ __launch_bounds__(256) void k_ypart(const float* __restrict__ x,
    const float* __restrict__ sct, const float* __restrict__ sumexp,
    const float* __restrict__ mu, const float* __restrict__ rstd,
    float* __restrict__ part, float* __restrict__ s1, float* __restrict__ out_attn) {
  __shared__ float rinv[56];
  __shared__ float amr[8][128];
  __shared__ float psm[56][128];
  __shared__ float s1sm[8];
  const int bid = blockIdx.x, tid = threadIdx.x;
  const int b = bid >> 6, ec = (bid >> 4) & 3, nc = bid & 15;
  const int row0 = b*NN + nc*128;
  if (tid < 56) rinv[tid] = 1.0f / sumexp[b*NHQ + tid];
  if (tid < 8) s1sm[tid] = 0.f;
  __syncthreads();
  for (int i = tid; i < 1024; i += 256) {
    const int h = i >> 7, nn = i & 127, row = row0 + nn;
    float amv = 0;
    #pragma unroll
    for (int q = 0; q < 7; q++) {
      float p = sct[(long)(h*7 + q)*NROWS + row] * rinv[h*7 + q];
      amv += p;
      psm[h*7 + q][nn] = p;
    }
    amv *= (1.0f/7.0f);
    amr[h][nn] = amv * rstd[row];
  }
  __syncthreads();
  if (ec == 0) {
    // out_attn[b,q,n] = mean_h p
    for (int i = tid; i < 896; i += 256) {
      const int q = i / 128, nn = i % 128;
      float s = 0;
      #pragma unroll
      for (int h = 0; h < 8; h++) s += psm[h*7 + q][nn];
      out_attn[((long)(b*NQ + q))*NN + nc*128 + nn] = s * 0.125f;
    }
    // s1[b,h] += sum_nn am*mu*rstd = amr*mu
    {
      const int h = tid >> 5, sl = tid & 31;
      float v = 0;
      #pragma unroll
      for (int nn = sl; nn < 128; nn += 32) v += amr[h][nn] * mu[row0 + nn];
      #pragma unroll
      for (int m = 1; m < 32; m <<= 1) v += __shfl_xor(v, m);
      if (sl == 0) atomicAdd(&s1[b*8 + h], v);
    }
  }
  const int e = ec*1024 + tid*4;
  float ax[8], ay[8], az[8], aw[8];
  #pragma unroll
  for (int h = 0; h < 8; h++) { ax[h]=0; ay[h]=0; az[h]=0; aw[h]=0; }
  const float* xp = x + (long)row0*DIM + e;
  #pragma unroll 2
  for (int nn = 0; nn < 128; nn++) {
    const float4 xv = *(const float4*)(xp + (long)nn*DIM);
    #pragma unroll
    for (int h = 0; h < 8; h++) {
      float a = amr[h][nn];
      ax[h] += a*xv.x; ay[h] += a*xv.y; az[h] += a*xv.z; aw[h] += a*xv.w;
    }
  }
  #pragma unroll
  for (int h = 0; h < 8; h++) {
    float4 o; o.x = ax[h]; o.y = ay[h]; o.z = az[h]; o.w = aw[h];
    *(float4*)&part[((long)(nc*64 + b*8 + h))*DIM + e] = o;
  }
}

// ---- K6: reduce 16 partials; ym = lng*(y - s1) + lnb
__global__ __launch_bounds__(256) void k_yred(const float* __restrict__ part,
    const float* __restrict__ s1, const float* __restrict__ lng, const float* __restrict__ lnb,
    float* __restrict__ ym) {
  const long i4 = (long)blockIdx.x*256 + threadIdx.x; // 65536 float4s
  const float4* p4 = (const float4*)part;
  float4 s = p4[i4];
  #pragma unroll
  for (int nc = 1; nc < 16; nc++) {
    float4 v = p4[(long)nc*65536 + i4];
    s.x += v.x; s.y += v.y; s.z += v.z; s.w += v.w;
  }
  const int bh = (int)(i4 >> 10), e4 = (int)(i4 & 1023);
  float sv = s1[bh];
  float4 g = ((const float4*)lng)[e4], bb = ((const float4*)lnb)[e4];
  float4 o;
  o.x = g.x*(s.x - sv) + bb.x; o.y = g.y*(s.y - sv) + bb.y;
  o.z = g.z*(s.z - sv) + bb.z; o.w = g.w*(s.w - sv) + bb.w;
  ((float4*)ym)[i4] = o;
}

// ---- K7: ctxm[b][d] = Wv_row(d).ym[b, d>>9, :] + bv[d]
__global__ __launch_bounds__(256) void k_ctxm(const float* __restrict__ ipw,
    const float* __restrict__ ipb, const float* __restrict__ ym, float* __restrict__ ctxm) {
  const int w = threadIdx.x >> 6, l = threadIdx.x & 63;
  const int d = blockIdx.x*4 + w;
  const int h = d >> 9;
  const float4* wr4 = (const float4*)(ipw + ((long)(2*DIM + d))*DIM);
  float acc[8] = {0,0,0,0,0,0,0,0};
  for (int e4 = l; e4 < 1024; e4 += 64) {
    float4 wv = wr4[e4];
    #pragma unroll
    for (int b = 0; b < 8; b++) {
      float4 y = ((const float4*)(ym + (long)(b*8 + h)*DIM))[e4];
      acc[b] += wv.x*y.x + wv.y*y.y + wv.z*y.z + wv.w*y.w;
    }
  }
  #pragma unroll
  for (int b = 0; b < 8; b++) acc[b] = waveSum(acc[b]);
  if (l == 0) {
    float bias = ipb[2*DIM + d];
    #pragma unroll
    for (int b = 0; b < 8; b++) ctxm[(long)b*DIM + d] = acc[b] + bias;
  }
}

// ---- K8: gfin[b][d] = tanh(alpha)*(sm[d] + opw_row(d).ctxm[b] + opb[d])
__global__ __launch_bounds__(256) void k_gvec(const float* __restrict__ opw,
    const float* __restrict__ opb, const float* __restrict__ ctxm, const float* __restrict__ slots,
    const float* __restrict__ alpha, float* __restrict__ gfin) {
  const int w = threadIdx.x >> 6, l = threadIdx.x & 63;
  const int d = blockIdx.x*4 + w;
  const float4* wr4 = (const float4*)(opw + (long)d*DIM);
  float acc[8] = {0,0,0,0,0,0,0,0};
  for (int e4 = l; e4 < 1024; e4 += 64) {
    float4 wv = wr4[e4];
    #pragma unroll
    for (int b = 0; b < 8; b++) {
      float4 c = ((const float4*)(ctxm + (long)b*DIM))[e4];
      acc[b] += wv.x*c.x + wv.y*c.y + wv.z*c.z + wv.w*c.w;
    }
  }
  #pragma unroll
  for (int b = 0; b < 8; b++) acc[b] = waveSum(acc[b]);
  if (l == 0) {
    float smv = 0;
    #pragma unroll
    for (int q = 0; q < 7; q++)
      smv += fminf(fmaxf(slots[(long)q*DIM + d], -10.f), 10.f);
    smv *= (1.0f/7.0f);
    float t = tanhf(alpha[0]);
    float base = smv + opb[d];
    #pragma unroll
    for (int b = 0; b < 8; b++) gfin[(long)b*DIM + d] = t * (base + acc[b]);
  }
}

// ---- K9: x_refined = x + g[b]
__global__ __launch_bounds__(256) void k_refine(const float* __restrict__ x,
    const float* __restrict__ gfin, float* __restrict__ out) {
  const float4* x4 = (const float4*)x;
  const float4* g4 = (const float4*)gfin;
  float4* o4 = (float4*)out;
  const long total = (long)NROWS * 1024;
  for (long i4 = (long)blockIdx.x*256 + threadIdx.x; i4 < total; i4 += (long)gridDim.x*256) {
    long b = i4 >> 21;
    long e4 = i4 & 1023;
    float4 xv = x4[i4], gv = g4[b*1024 + e4];
    float4 o; o.x = xv.x + gv.x; o.y = xv.y + gv.y; o.z = xv.z + gv.z; o.w = xv.w + gv.w;
    o4[i4] = o;
  }
}

extern "C" void kernel_launch(void* const* d_in, const int* in_sizes, int n_in,
                              void* d_out, int out_size, void* d_ws, size_t ws_size,
                              hipStream_t stream) {
  const float* x     = (const float*)d_in[0];
  const float* slots = (const float*)d_in[1];
  const float* lng   = (const float*)d_in[2];
  const float* lnb   = (const float*)d_in[3];
  const float* ipw   = (const float*)d_in[4];
  const float* ipb   = (const float*)d_in[5];
  const float* opw   = (const float*)d_in[6];
  const float* opb   = (const float*)d_in[7];
  const float* alpha = (const float*)d_in[8];
  float* out = (float*)d_out;
  float* ws  = (float*)d_ws;

  float* mu     = ws + OFF_MU;
  float* rstd   = ws + OFF_RSTD;
  float* q7     = ws + OFF_Q7;
  float* Aarr   = ws + OFF_A;
  float* D0arr  = ws + OFF_D0;
  float* s1     = ws + OFF_S1;
  float* sumexp = ws + OFF_SUMEXP;
  float* ctxm   = ws + OFF_CTXM;
  float* gfin   = ws + OFF_GFIN;
  float* ym     = ws + OFF_YM;
  unsigned short* ugbf = (unsigned short*)(ws + OFF_UGBF);
  float* sct    = ws + OFF_SCT;
  float* upart  = ws + OFF_BIG;
  float* part   = ws + OFF_PART;
  float* out_attn = out + (long)NROWS * DIM;

  hipLaunchKernelGGL(k_pre,    dim3(1024), dim3(256), 0, stream, ipw, ipb, slots, q7, ws);
  hipLaunchKernelGGL(k_uproj,  dim3(512),  dim3(256), 0, stream, ipw, ipb, q7, upart, D0arr);
  hipLaunchKernelGGL(k_ured,   dim3(128),  dim3(256), 0, stream, upart, lng, lnb, ugbf, Aarr, D0arr);
  hipLaunchKernelGGL(k_scores, dim3(512),  dim3(128), 0, stream, x, ugbf, Aarr, D0arr, mu, rstd, sct, sumexp);
  hipLaunchKernelGGL(k_ypart,  dim3(512),  dim3(256), 0, stream, x, sct, sumexp, mu, rstd, part, s1, out_attn);
  hipLaunchKernelGGL(k_yred,   dim3(256),  dim3(256), 0, stream, part, s1, lng, lnb, ym);
  hipLaunchKernelGGL(k_ctxm,   dim3(1024), dim3(256), 0, stream, ipw, ipb, ym, ctxm);
  hipLaunchKernelGGL(k_gvec,   dim3(1024), dim3(256), 0, stream, opw, opb, ctxm, slots, alpha, gfin);
  hipLaunchKernelGGL(k_refine, dim3(8192), dim3(256), 0, stream, x, gfin, out);
}